// Round 12
// baseline (306.984 us; speedup 1.0000x reference)
//
#include <hip/hip_runtime.h>
#include <hip/hip_bf16.h>
#include <stdint.h>

#define S_LEN 2048
#define DM    2048
#define NH    32
#define NG    8
#define DK    64
#define BATCH 2
#define MROWS (BATCH*S_LEN)   /* 4096 */
#define NQKV  3072            /* 2048 Q + 512 K + 512 V */
#define SSCALE 0.18033688f    /* (1/8) * log2(e), folded into Qb */

typedef __bf16 bf16x8 __attribute__((ext_vector_type(8)));
typedef short  s16x8  __attribute__((ext_vector_type(8)));
typedef float  f32x4  __attribute__((ext_vector_type(4)));
typedef unsigned int u32x4 __attribute__((ext_vector_type(4)));

__device__ __forceinline__ unsigned short f2b(float f) {
    unsigned int x = __float_as_uint(f);
    unsigned int r = (x + 0x7fffu + ((x >> 16) & 1u)) >> 16;
    return (unsigned short)r;
}
__device__ __forceinline__ bf16x8 ld8(const unsigned short* p) {
    return *(const bf16x8*)p;
}
__device__ __forceinline__ s16x8 cvt8(const float* p) {
    f32x4 a = *(const f32x4*)p;
    f32x4 b = *(const f32x4*)(p + 4);
    s16x8 o;
#pragma unroll
    for (int j = 0; j < 4; j++) { o[j] = (short)f2b(a[j]); o[4 + j] = (short)f2b(b[j]); }
    return o;
}
// async global->LDS, 16 B per lane; lds dest = uniform base + lane*16
__device__ __forceinline__ void gl_lds(const unsigned short* g, unsigned short* l) {
    __builtin_amdgcn_global_load_lds(
        (const __attribute__((address_space(1))) unsigned int*)g,
        (__attribute__((address_space(3))) unsigned int*)l, 16, 0, 0);
}
__device__ __forceinline__ void wait_vm4() {
    asm volatile("s_waitcnt vmcnt(4)" ::: "memory");
}
__device__ __forceinline__ void wait_vm0() {
    asm volatile("s_waitcnt vmcnt(0)" ::: "memory");
}
__device__ __forceinline__ void bar() {
    __builtin_amdgcn_sched_barrier(0);
    __builtin_amdgcn_s_barrier();
    __builtin_amdgcn_sched_barrier(0);
}

// ============ fused pre-pass: cvt_x + 4 weight transposes + bias concat =====
// v13: transpose tiles are 32 cols x 64 rows -> stores are 64 consecutive
// bf16 = 128B full cache lines (was 64B half-lines); block count halves.
// LDS t[32][65]: load lanes stride 65 (conflict-free), store lanes stride 1.
#define TCVT 4096   /* x fp32->bf16, 2048 elems/block */
#define TQ   2048   /* Wq 32x64 tiles */
#define TK   512    /* Wk */
#define TV   512    /* Wv */
#define TO   2048   /* Wo */
#define TB   12     /* bias 3072 elems */
#define NPREP (TCVT+TQ+TK+TV+TO+TB)
__global__ __launch_bounds__(256) void prep_fused(
    const float* __restrict__ x,
    const float* __restrict__ Wq, const float* __restrict__ Wk,
    const float* __restrict__ Wv, const float* __restrict__ Wo,
    const float* __restrict__ bq, const float* __restrict__ bk,
    const float* __restrict__ bv,
    unsigned short* __restrict__ xb,
    unsigned short* __restrict__ WqkvT, unsigned short* __restrict__ WoT,
    float* __restrict__ bqkv) {
    __shared__ float t[32][65];
    int bid = blockIdx.x;
    const int tx = threadIdx.x, ty = threadIdx.y;
    const int flat = ty * 32 + tx;
    if (bid < TCVT) {
        size_t id = (size_t)bid * 256 + flat;
        *(s16x8*)&xb[id * 8] = cvt8(x + id * 8);
        return;
    }
    bid -= TCVT;
    const float* in; unsigned short* out; int C, bx, by;
    if (bid < TQ) { in = Wq; out = WqkvT; C = DM; bx = bid & 63; by = bid >> 6; }
    else if ((bid -= TQ) < TK) { in = Wk; out = WqkvT + (size_t)2048 * DM; C = 512; bx = bid & 15; by = bid >> 4; }
    else if ((bid -= TK) < TV) { in = Wv; out = WqkvT + (size_t)2560 * DM; C = 512; bx = bid & 15; by = bid >> 4; }
    else if ((bid -= TV) < TO) { in = Wo; out = WoT; C = DM; bx = bid & 63; by = bid >> 6; }
    else {
        int i = (bid - TO) * 256 + flat;
        if (i < 2048) bqkv[i] = bq[i];
        else if (i < 2560) bqkv[i] = bk[i - 2048];
        else if (i < 3072) bqkv[i] = bv[i - 2560];
        return;
    }
    int c0 = bx * 32, r0 = by * 64;
#pragma unroll
    for (int i = 0; i < 8; i++)
        t[tx][ty + i * 8] = in[(size_t)(r0 + ty + i * 8) * C + c0 + tx];
    __syncthreads();
    const int rt = flat & 63, cg = flat >> 6;
#pragma unroll
    for (int i = 0; i < 8; i++)
        out[(size_t)(c0 + cg * 8 + i) * DM + r0 + rt] = f2b(t[cg * 8 + i][rt]);
}

// XCD-aware bijective remap (grid count divisible by 8): blocks resident on
// one XCD get a contiguous chunk of work-tiles -> shared B^T panel L2-hits.
__device__ __forceinline__ void xcd_remap(int gx, int* bx, int* by) {
    int nwg = gx * (int)gridDim.y;
    int flat = (int)blockIdx.y * gx + (int)blockIdx.x;
    int wgid = (flat & 7) * (nwg >> 3) + (flat >> 3);
    *bx = wgid % gx;
    *by = wgid / gx;
}

// ============ fused QKV GEMM: xb[4096,2048]bf16 x WqkvT[3072,2048] ==========
// UNCHANGED from v12 (cross-run variance control: 103us this run vs <=83 in
// R10 with identical source). 128x128, 3-buffer counted vmcnt(4), XCD remap.
__global__ __launch_bounds__(256, 3) void gemm_qkv(const unsigned short* __restrict__ A,
                                                const unsigned short* __restrict__ Bt,
                                                const float* __restrict__ bias,
                                                unsigned short* __restrict__ Qb,
                                                float* __restrict__ Kg, float* __restrict__ Vg,
                                                unsigned short* __restrict__ Kb,
                                                unsigned short* __restrict__ Vtb) {
    __shared__ alignas(16) unsigned short As[3][128 * 32];
    __shared__ alignas(16) unsigned short Bs[3][128 * 32];
    const int K = DM;
    const int tid = threadIdx.x;
    int bx, by;
    xcd_remap(NQKV / 128, &bx, &by);
    const int n0 = bx * 128, m0 = by * 128;
    const int w = tid >> 6, lane = tid & 63;
    const int ln15 = lane & 15, quad = lane >> 4;
    const int wm = (w >> 1) * 64, wn = (w & 1) * 64;
    const int xq = (quad ^ ((ln15 >> 1) & 3)) * 8;   // conflict-free frag slot
    f32x4 acc[4][4] = {};

#define GSTAGE(k0v, buf) do {                                                    \
    _Pragma("unroll")                                                            \
    for (int i = 0; i < 2; ++i) {                                                \
        int s = w * 128 + i * 64 + lane;       /* slot 0..511 (16B each) */      \
        int r = s >> 2, cb = (s & 3) ^ ((r >> 1) & 3);                           \
        gl_lds(&A[(size_t)(m0 + r) * K + (k0v) + cb * 8],                        \
               &As[buf][(w * 128 + i * 64) * 8]);                                \
        gl_lds(&Bt[(size_t)(n0 + r) * K + (k0v) + cb * 8],                       \
               &Bs[buf][(w * 128 + i * 64) * 8]);                                \
    } } while (0)

    GSTAGE(0, 0);
    GSTAGE(32, 1);
    int cur = 0;
    for (int k0 = 0; k0 < K; k0 += 32) {
        if (k0 + 32 < K) wait_vm4(); else wait_vm0();
        bar();
        if (k0 + 64 < K) {
            int nb = cur + 2; if (nb >= 3) nb -= 3;
            GSTAGE(k0 + 64, nb);
        }
        bf16x8 af[4], bfr[4];
#pragma unroll
        for (int mt = 0; mt < 4; mt++)
            af[mt] = ld8(&As[cur][(wm + mt * 16 + ln15) * 32 + xq]);
#pragma unroll
        for (int nt = 0; nt < 4; nt++)
            bfr[nt] = ld8(&Bs[cur][(wn + nt * 16 + ln15) * 32 + xq]);
        __builtin_amdgcn_s_setprio(1);
#pragma unroll
        for (int mt = 0; mt < 4; mt++)
#pragma unroll
            for (int nt = 0; nt < 4; nt++)
                acc[mt][nt] = __builtin_amdgcn_mfma_f32_16x16x32_bf16(af[mt], bfr[nt], acc[mt][nt], 0, 0, 0);
        __builtin_amdgcn_s_setprio(0);
        cur = (cur + 1 == 3) ? 0 : cur + 1;
    }
#undef GSTAGE
#pragma unroll
    for (int nt = 0; nt < 4; nt++) {
        int col = n0 + wn + nt * 16 + ln15;
        float bv = bias[col];
#pragma unroll
        for (int mt = 0; mt < 4; mt++) {
            int row0 = m0 + wm + mt * 16 + quad * 4;
#pragma unroll
            for (int r = 0; r < 4; r++) {
                float val = acc[mt][nt][r] + bv;
                int row = row0 + r;
                int b = row >> 11, s = row & 2047;
                if (col < 2048) {
                    // fold softmax scale into Q (f32 mul before bf16 round)
                    Qb[(size_t)row * DM + col] = f2b(val * SSCALE);
                } else if (col < 2560) {
                    int gc = col - 2048, g = gc >> 6, d = gc & 63;
                    size_t idx = (((size_t)(b * NG + g) * S_LEN + s) << 6) + d;
                    Kg[idx] = val;
                    Kb[idx] = f2b(val);
                } else {
                    int gc = col - 2560, g = gc >> 6, d = gc & 63;
                    Vg[(((size_t)(b * NG + g) * S_LEN + s) << 6) + d] = val;
                    Vtb[((size_t)(b * NG + g) * DK + d) * S_LEN + s] = f2b(val);
                }
            }
        }
    }
}

// ============ O-projection v13: BK=64 double-sub-tile (attn-v12 pattern) ====
// 2 buffers x 2 sub-tiles of 32-K each; one vmcnt(0)+barrier per 64-K ->
// barrier-pairs halve (32->16), 32 MFMA between barriers. LDS 64KB ->
// 2 blocks/CU; grid 16x32 = 512 = exact 2/CU fill.
__global__ __launch_bounds__(256, 2) void gemm_o(const unsigned short* __restrict__ A,
                                              const unsigned short* __restrict__ Bt,
                                              const float* __restrict__ bias,
                                              float* __restrict__ C) {
    __shared__ alignas(16) unsigned short As[2][2][128 * 32];
    __shared__ alignas(16) unsigned short Bs[2][2][128 * 32];
    const int K = DM, N = DM;
    const int tid = threadIdx.x;
    int bx, by;
    xcd_remap(DM / 128, &bx, &by);
    const int n0 = bx * 128, m0 = by * 128;
    const int w = tid >> 6, lane = tid & 63;
    const int ln15 = lane & 15, quad = lane >> 4;
    const int wm = (w >> 1) * 64, wn = (w & 1) * 64;
    const int xq = (quad ^ ((ln15 >> 1) & 3)) * 8;
    f32x4 acc[4][4] = {};

#define GSTAGE64(k0v, buf) do {                                                  \
    _Pragma("unroll")                                                            \
    for (int j = 0; j < 2; ++j) {                                                \
        _Pragma("unroll")                                                        \
        for (int i = 0; i < 2; ++i) {                                            \
            int s = w * 128 + i * 64 + lane;                                     \
            int r = s >> 2, cb = (s & 3) ^ ((r >> 1) & 3);                       \
            gl_lds(&A[(size_t)(m0 + r) * K + (k0v) + j * 32 + cb * 8],           \
                   &As[buf][j][(w * 128 + i * 64) * 8]);                         \
            gl_lds(&Bt[(size_t)(n0 + r) * K + (k0v) + j * 32 + cb * 8],          \
                   &Bs[buf][j][(w * 128 + i * 64) * 8]);                         \
        }                                                                        \
    } } while (0)

    GSTAGE64(0, 0);
    wait_vm0();
    __syncthreads();
    int cur = 0;
    for (int k0 = 0; k0 < K; k0 += 64) {
        if (k0 + 64 < K) GSTAGE64(k0 + 64, cur ^ 1);   // prefetch next 64-slice
#pragma unroll
        for (int sub = 0; sub < 2; sub++) {
            bf16x8 af[4], bfr[4];
#pragma unroll
            for (int mt = 0; mt < 4; mt++)
                af[mt] = ld8(&As[cur][sub][(wm + mt * 16 + ln15) * 32 + xq]);
#pragma unroll
            for (int nt = 0; nt < 4; nt++)
                bfr[nt] = ld8(&Bs[cur][sub][(wn + nt * 16 + ln15) * 32 + xq]);
            __builtin_amdgcn_s_setprio(1);
#pragma unroll
            for (int mt = 0; mt < 4; mt++)
#pragma unroll
                for (int nt = 0; nt < 4; nt++)
                    acc[mt][nt] = __builtin_amdgcn_mfma_f32_16x16x32_bf16(af[mt], bfr[nt], acc[mt][nt], 0, 0, 0);
            __builtin_amdgcn_s_setprio(0);
        }
        wait_vm0();          // drain prefetch before buffer flip
        __syncthreads();
        cur ^= 1;
    }
#undef GSTAGE64
#pragma unroll
    for (int nt = 0; nt < 4; nt++) {
        int col = n0 + wn + nt * 16 + ln15;
        float bv = bias[col];
#pragma unroll
        for (int mt = 0; mt < 4; mt++) {
            int row0 = m0 + wm + mt * 16 + quad * 4;
#pragma unroll
            for (int r = 0; r < 4; r++)
                C[(size_t)(row0 + r) * N + col] = acc[mt][nt][r] + bv;
        }
    }
}

// ============ flash attention v12 (kept): KVBLK=128, 512 threads ============
#define MT 2                 /* 16-row mfma blocks per wave */
__global__ __launch_bounds__(512, 4) void attn_fwd(const unsigned short* __restrict__ Qb,
                                                   const unsigned short* __restrict__ Kb,
                                                   const unsigned short* __restrict__ Vtb,
                                                   unsigned short* __restrict__ AO) {
    __shared__ alignas(16) unsigned short Ks[2][2][64 * 64];  // [buf][sub][r][cb^(r&7)]
    __shared__ alignas(16) unsigned short Vt[2][2][64 * 64];  // rows = d
    const int b = blockIdx.z, h = blockIdx.y, q0 = blockIdx.x * 256;
    const int g = h >> 2;
    const int tid = threadIdx.x;
    const int w = tid >> 6, lane = tid & 63;
    const int ln15 = lane & 15, quad = lane >> 4;
    const int x7a = (quad ^ (ln15 & 7)) * 8;        // k-block 0..3 swizzled
    const int x7b = x7a ^ 32;                       // k-block 4..7 swizzled

    // Q fragments for this wave's 32 q rows (MT mfma row-blocks); pre-scaled
    bf16x8 aq[MT][2];
#pragma unroll
    for (int mt = 0; mt < MT; mt++) {
        const size_t qrow =
            ((size_t)(b * S_LEN + q0 + w * 32 + mt * 16 + ln15)) * DM + h * DK;
        aq[mt][0] = ld8(&Qb[qrow + quad * 8]);
        aq[mt][1] = ld8(&Qb[qrow + 32 + quad * 8]);
    }

    bf16x8 ones;
#pragma unroll
    for (int j = 0; j < 8; j++) ones[j] = (__bf16)1.0f;

    f32x4 o[MT][4] = {};     // [mt][nt]  D[q][d]: col=ln15, row=quad*4+r
    f32x4 l_acc[MT] = {};    // [mt]
    const size_t kvb = ((size_t)(b * NG + g)) * S_LEN * DK;

    // 512 threads: per sub-tile, one K + one V gl_lds per thread (512 slots).
#define STAGE(k0v, buf) do {                                                     \
    int r = tid >> 3, cb = (tid & 7) ^ (r & 7);                                  \
    _Pragma("unroll")                                                            \
    for (int j = 0; j < 2; j++) {                                                \
        gl_lds(&Kb[kvb + (size_t)((k0v) + j * 64 + r) * DK + cb * 8],            \
               &Ks[buf][j][(w * 64) * 8]);                                       \
        gl_lds(&Vtb[kvb + (size_t)r * S_LEN + (k0v) + j * 64 + cb * 8],          \
               &Vt[buf][j][(w * 64) * 8]);                                       \
    } } while (0)

    STAGE(0, 0);
    wait_vm0();
    __syncthreads();
    int cur = 0;

    for (int k0 = 0; k0 < S_LEN; k0 += 128) {
        if (k0 + 128 < S_LEN) STAGE(k0 + 128, cur ^ 1);   // prefetch next pair

#pragma unroll
        for (int sub = 0; sub < 2; sub++) {
            // ---- QK^T (swapped): z[mt][nt] = D[key][q=mt*16+ln15]
            f32x4 z[MT][4];
            __builtin_amdgcn_s_setprio(1);
#pragma unroll
            for (int nt = 0; nt < 4; nt++) {
                bf16x8 bk0 = ld8(&Ks[cur][sub][(nt * 16 + ln15) * 64 + x7a]);
                bf16x8 bk1 = ld8(&Ks[cur][sub][(nt * 16 + ln15) * 64 + x7b]);
#pragma unroll
                for (int mt = 0; mt < MT; mt++) {
                    f32x4 t = {0.f, 0.f, 0.f, 0.f};
                    t = __builtin_amdgcn_mfma_f32_16x16x32_bf16(bk0, aq[mt][0], t, 0, 0, 0);
                    t = __builtin_amdgcn_mfma_f32_16x16x32_bf16(bk1, aq[mt][1], t, 0, 0, 0);
                    z[mt][nt] = t;
                }
            }
            __builtin_amdgcn_s_setprio(0);

            // ---- exp2 + pack + in-register transpose to PV A-fragments ----
            bf16x8 pa[MT][2];
#pragma unroll
            for (int mt = 0; mt < MT; mt++) {
                unsigned int S[4][2];
#pragma unroll
                for (int nt = 0; nt < 4; nt++) {
                    f32x4 pe;
#pragma unroll
                    for (int r = 0; r < 4; r++)
                        pe[r] = __builtin_amdgcn_exp2f(z[mt][nt][r]);
                    asm("v_cvt_pk_bf16_f32 %0, %1, %2" : "=v"(S[nt][0]) : "v"(pe[0]), "v"(pe[1]));
                    asm("v_cvt_pk_bf16_f32 %0, %1, %2" : "=v"(S[nt][1]) : "v"(pe[2]), "v"(pe[3]));
                }
#pragma unroll
                for (int f = 0; f < 2; f++) {
                    unsigned int wA[2], wB[2];
#pragma unroll
                    for (int p = 0; p < 2; p++) {
                        unsigned int xa = S[2 * f][p], yb = S[2 * f + 1][p];
                        asm("v_permlane32_swap_b32 %0, %1" : "+v"(xa), "+v"(yb));
                        asm("v_permlane16_swap_b32 %0, %1" : "+v"(xa), "+v"(yb));
                        wA[p] = xa; wB[p] = yb;
                    }
                    u32x4 t4;
                    t4[0] = wA[0]; t4[1] = wA[1]; t4[2] = wB[0]; t4[3] = wB[1];
                    pa[mt][f] = __builtin_bit_cast(bf16x8, t4);
                }
            }

            // ---- PV: nt outer so each V fragment is read once ----
            __builtin_amdgcn_s_setprio(1);
#pragma unroll
            for (int nt = 0; nt < 4; nt++) {
                bf16x8 bv0 = ld8(&Vt[cur][sub][(nt * 16 + ln15) * 64 + x7a]);
                bf16x8 bv1 = ld8(&Vt[cur][sub][(nt * 16 + ln15) * 64 + x7b]);
#pragma unroll
                for (int mt = 0; mt < MT; mt++) {
                    f32x4 t = o[mt][nt];
                    t = __builtin_amdgcn_mfma_f32_16x16x32_bf16(pa[mt][0], bv0, t, 0, 0, 0);
                    t = __builtin_amdgcn_mfma_f32_16x16x32_bf16(pa[mt][1], bv1, t, 0, 0, 0);
                    o[mt][nt] = t;
                }
            }
#pragma unroll
            for (int mt = 0; mt < MT; mt++) {
                l_acc[mt] = __builtin_amdgcn_mfma_f32_16x16x32_bf16(pa[mt][0], ones, l_acc[mt], 0, 0, 0);
                l_acc[mt] = __builtin_amdgcn_mfma_f32_16x16x32_bf16(pa[mt][1], ones, l_acc[mt], 0, 0, 0);
            }
            __builtin_amdgcn_s_setprio(0);
        }

        wait_vm0();          // drain prefetch before buffer flip
        __syncthreads();
        cur ^= 1;
    }
#undef STAGE

#pragma unroll
    for (int mt = 0; mt < MT; mt++) {
#pragma unroll
        for (int r = 0; r < 4; r++) {
            float inv = 1.0f / l_acc[mt][r];
            int q = q0 + w * 32 + mt * 16 + quad * 4 + r;
#pragma unroll
            for (int nt = 0; nt < 4; nt++) {
                int col = h * DK + nt * 16 + ln15;
                *(__bf16*)&AO[((size_t)(b * S_LEN + q)) * DM + col] =
                    (__bf16)(o[mt][nt][r] * inv);
            }
        }
    }
}

extern "C" void kernel_launch(void* const* d_in, const int* in_sizes, int n_in,
                              void* d_out, int out_size, void* d_ws, size_t ws_size,
                              hipStream_t stream) {
    const float* x  = (const float*)d_in[0];
    const float* Wq = (const float*)d_in[1];
    const float* bq = (const float*)d_in[2];
    const float* Wk = (const float*)d_in[3];
    const float* bk = (const float*)d_in[4];
    const float* Wv = (const float*)d_in[5];
    const float* bv = (const float*)d_in[6];
    const float* Wo = (const float*)d_in[7];
    const float* bo = (const float*)d_in[8];

    float* out = (float*)d_out;                         // [4096, 2048] f32
    float* Kg  = out + (size_t)MROWS * DM;              // (B,G,S,dk) f32
    float* Vg  = Kg + (size_t)BATCH * NG * S_LEN * DK;

    // Qb bf16 [4096,2048] parks in the out region (proven safe rounds 4-5);
    // it is only READ via plain vector loads, never via global_load_lds.
    unsigned short* Qb = (unsigned short*)d_out;

    // workspace layout (62.93 MB). All global_load_lds sources live here.
    unsigned short* ws    = (unsigned short*)d_ws;
    unsigned short* WqkvT = ws;                                   // [3072,2048] bf16
    unsigned short* WoT   = WqkvT + (size_t)NQKV * DM;            // [2048,2048] bf16
    unsigned short* Kb    = WoT + (size_t)DM * DM;                // (B,G,S,dk) bf16
    unsigned short* Vtb   = Kb + (size_t)BATCH * NG * S_LEN * DK; // (B,G,dk,S) bf16
    unsigned short* AO    = Vtb + (size_t)BATCH * NG * S_LEN * DK;// [4096,2048] bf16
    unsigned short* xb    = AO + (size_t)MROWS * DM;              // [4096,2048] bf16
    float*          bqkv  = (float*)(xb + (size_t)MROWS * DM);    // [3072] f32

    hipLaunchKernelGGL(prep_fused, dim3(NPREP), dim3(32, 8), 0, stream,
                       x, Wq, Wk, Wv, Wo, bq, bk, bv, xb, WqkvT, WoT, bqkv);

    hipLaunchKernelGGL(gemm_qkv, dim3(NQKV / 128, MROWS / 128), dim3(256), 0, stream,
                       xb, WqkvT, bqkv, Qb, Kg, Vg, Kb, Vtb);

    hipLaunchKernelGGL(attn_fwd, dim3(S_LEN / 256, NH, BATCH), dim3(512), 0, stream,
                       Qb, Kb, Vtb, AO);

    hipLaunchKernelGGL(gemm_o, dim3(DM / 128, MROWS / 128), dim3(256), 0, stream,
                       AO, WoT, bo, out);
}

// Round 13
// 304.797 us; speedup vs baseline: 1.0072x; 1.0072x over previous
//
#include <hip/hip_runtime.h>
#include <hip/hip_bf16.h>
#include <stdint.h>

#define S_LEN 2048
#define DM    2048
#define NH    32
#define NG    8
#define DK    64
#define BATCH 2
#define MROWS (BATCH*S_LEN)   /* 4096 */
#define NQKV  3072            /* 2048 Q + 512 K + 512 V */
#define SSCALE 0.18033688f    /* (1/8) * log2(e), folded into Qb */

typedef __bf16 bf16x8 __attribute__((ext_vector_type(8)));
typedef short  s16x8  __attribute__((ext_vector_type(8)));
typedef float  f32x4  __attribute__((ext_vector_type(4)));
typedef unsigned int u32x4 __attribute__((ext_vector_type(4)));

__device__ __forceinline__ unsigned short f2b(float f) {
    unsigned int x = __float_as_uint(f);
    unsigned int r = (x + 0x7fffu + ((x >> 16) & 1u)) >> 16;
    return (unsigned short)r;
}
__device__ __forceinline__ bf16x8 ld8(const unsigned short* p) {
    return *(const bf16x8*)p;
}
__device__ __forceinline__ s16x8 cvt8(const float* p) {
    f32x4 a = *(const f32x4*)p;
    f32x4 b = *(const f32x4*)(p + 4);
    s16x8 o;
#pragma unroll
    for (int j = 0; j < 4; j++) { o[j] = (short)f2b(a[j]); o[4 + j] = (short)f2b(b[j]); }
    return o;
}
// async global->LDS, 16 B per lane; lds dest = uniform base + lane*16
__device__ __forceinline__ void gl_lds(const unsigned short* g, unsigned short* l) {
    __builtin_amdgcn_global_load_lds(
        (const __attribute__((address_space(1))) unsigned int*)g,
        (__attribute__((address_space(3))) unsigned int*)l, 16, 0, 0);
}
__device__ __forceinline__ void wait_vm4() {
    asm volatile("s_waitcnt vmcnt(4)" ::: "memory");
}
__device__ __forceinline__ void wait_vm0() {
    asm volatile("s_waitcnt vmcnt(0)" ::: "memory");
}
__device__ __forceinline__ void bar() {
    __builtin_amdgcn_sched_barrier(0);
    __builtin_amdgcn_s_barrier();
    __builtin_amdgcn_sched_barrier(0);
}

// ============ fused pre-pass: cvt_x + 4 weight transposes + bias concat =====
// v13 transpose: 32 cols x 64 rows tiles -> 128B full-line stores.
#define TCVT 4096   /* x fp32->bf16, 2048 elems/block */
#define TQ   2048   /* Wq 32x64 tiles */
#define TK   512    /* Wk */
#define TV   512    /* Wv */
#define TO   2048   /* Wo */
#define TB   12     /* bias 3072 elems */
#define NPREP (TCVT+TQ+TK+TV+TO+TB)
__global__ __launch_bounds__(256) void prep_fused(
    const float* __restrict__ x,
    const float* __restrict__ Wq, const float* __restrict__ Wk,
    const float* __restrict__ Wv, const float* __restrict__ Wo,
    const float* __restrict__ bq, const float* __restrict__ bk,
    const float* __restrict__ bv,
    unsigned short* __restrict__ xb,
    unsigned short* __restrict__ WqkvT, unsigned short* __restrict__ WoT,
    float* __restrict__ bqkv) {
    __shared__ float t[32][65];
    int bid = blockIdx.x;
    const int tx = threadIdx.x, ty = threadIdx.y;
    const int flat = ty * 32 + tx;
    if (bid < TCVT) {
        size_t id = (size_t)bid * 256 + flat;
        *(s16x8*)&xb[id * 8] = cvt8(x + id * 8);
        return;
    }
    bid -= TCVT;
    const float* in; unsigned short* out; int C, bx, by;
    if (bid < TQ) { in = Wq; out = WqkvT; C = DM; bx = bid & 63; by = bid >> 6; }
    else if ((bid -= TQ) < TK) { in = Wk; out = WqkvT + (size_t)2048 * DM; C = 512; bx = bid & 15; by = bid >> 4; }
    else if ((bid -= TK) < TV) { in = Wv; out = WqkvT + (size_t)2560 * DM; C = 512; bx = bid & 15; by = bid >> 4; }
    else if ((bid -= TV) < TO) { in = Wo; out = WoT; C = DM; bx = bid & 63; by = bid >> 6; }
    else {
        int i = (bid - TO) * 256 + flat;
        if (i < 2048) bqkv[i] = bq[i];
        else if (i < 2560) bqkv[i] = bk[i - 2048];
        else if (i < 3072) bqkv[i] = bv[i - 2560];
        return;
    }
    int c0 = bx * 32, r0 = by * 64;
#pragma unroll
    for (int i = 0; i < 8; i++)
        t[tx][ty + i * 8] = in[(size_t)(r0 + ty + i * 8) * C + c0 + tx];
    __syncthreads();
    const int rt = flat & 63, cg = flat >> 6;
#pragma unroll
    for (int i = 0; i < 8; i++)
        out[(size_t)(c0 + cg * 8 + i) * DM + r0 + rt] = f2b(t[cg * 8 + i][rt]);
}

// XCD-aware bijective remap (grid count divisible by 8): blocks resident on
// one XCD get a contiguous chunk of work-tiles -> shared B^T panel L2-hits.
__device__ __forceinline__ void xcd_remap(int gx, int* bx, int* by) {
    int nwg = gx * (int)gridDim.y;
    int flat = (int)blockIdx.y * gx + (int)blockIdx.x;
    int wgid = (flat & 7) * (nwg >> 3) + (flat >> 3);
    *bx = wgid % gx;
    *by = wgid / gx;
}

// ============ fused QKV GEMM: xb[4096,2048]bf16 x WqkvT[3072,2048] ==========
// v14: main loop unchanged (128x128, 3-buffer counted vmcnt(4), XCD remap).
// NEW: K/V-region blocks stage their bf16 tile in the (dead) staging LDS and
// write Kb/Vtb as 128B-contiguous runs -- kills the 8B/4KB-stride scatter
// that amplified WRITE_SIZE 57MB vs 28 legit.
__global__ __launch_bounds__(256, 3) void gemm_qkv(const unsigned short* __restrict__ A,
                                                const unsigned short* __restrict__ Bt,
                                                const float* __restrict__ bias,
                                                unsigned short* __restrict__ Qb,
                                                float* __restrict__ Kg, float* __restrict__ Vg,
                                                unsigned short* __restrict__ Kb,
                                                unsigned short* __restrict__ Vtb) {
    // one carved pool: As(b)=lds+b*4096, Bs(b)=lds+12288+b*4096 (48KB total);
    // epilogue vbuf[128][136] (34KB) reuses the same pool after the K-loop.
    __shared__ alignas(16) unsigned short lds[24576];
#define AS(b) (lds + (b) * 4096)
#define BS(b) (lds + 12288 + (b) * 4096)
    const int K = DM;
    const int tid = threadIdx.x;
    int bx, by;
    xcd_remap(NQKV / 128, &bx, &by);
    const int n0 = bx * 128, m0 = by * 128;
    const int w = tid >> 6, lane = tid & 63;
    const int ln15 = lane & 15, quad = lane >> 4;
    const int wm = (w >> 1) * 64, wn = (w & 1) * 64;
    const int xq = (quad ^ ((ln15 >> 1) & 3)) * 8;   // conflict-free frag slot
    f32x4 acc[4][4] = {};

#define GSTAGE(k0v, buf) do {                                                    \
    _Pragma("unroll")                                                            \
    for (int i = 0; i < 2; ++i) {                                                \
        int s = w * 128 + i * 64 + lane;       /* slot 0..511 (16B each) */      \
        int r = s >> 2, cb = (s & 3) ^ ((r >> 1) & 3);                           \
        gl_lds(&A[(size_t)(m0 + r) * K + (k0v) + cb * 8],                        \
               AS(buf) + (w * 128 + i * 64) * 8);                                \
        gl_lds(&Bt[(size_t)(n0 + r) * K + (k0v) + cb * 8],                       \
               BS(buf) + (w * 128 + i * 64) * 8);                                \
    } } while (0)

    GSTAGE(0, 0);
    GSTAGE(32, 1);
    int cur = 0;
    for (int k0 = 0; k0 < K; k0 += 32) {
        if (k0 + 32 < K) wait_vm4(); else wait_vm0();
        bar();
        if (k0 + 64 < K) {
            int nb = cur + 2; if (nb >= 3) nb -= 3;
            GSTAGE(k0 + 64, nb);
        }
        bf16x8 af[4], bfr[4];
#pragma unroll
        for (int mt = 0; mt < 4; mt++)
            af[mt] = ld8(AS(cur) + (wm + mt * 16 + ln15) * 32 + xq);
#pragma unroll
        for (int nt = 0; nt < 4; nt++)
            bfr[nt] = ld8(BS(cur) + (wn + nt * 16 + ln15) * 32 + xq);
        __builtin_amdgcn_s_setprio(1);
#pragma unroll
        for (int mt = 0; mt < 4; mt++)
#pragma unroll
            for (int nt = 0; nt < 4; nt++)
                acc[mt][nt] = __builtin_amdgcn_mfma_f32_16x16x32_bf16(af[mt], bfr[nt], acc[mt][nt], 0, 0, 0);
        __builtin_amdgcn_s_setprio(0);
        cur = (cur + 1 == 3) ? 0 : cur + 1;
    }
#undef GSTAGE

    const int bb = m0 >> 11, s0 = m0 & 2047;   // block-uniform batch / seq base
    if (n0 < 2048) {
        // ---- Q region: full-line writes, unchanged ----
#pragma unroll
        for (int nt = 0; nt < 4; nt++) {
            int col = n0 + wn + nt * 16 + ln15;
            float bv = bias[col];
#pragma unroll
            for (int mt = 0; mt < 4; mt++) {
                int row0 = m0 + wm + mt * 16 + quad * 4;
#pragma unroll
                for (int r = 0; r < 4; r++)
                    Qb[(size_t)(row0 + r) * DM + col] = f2b((acc[mt][nt][r] + bv) * SSCALE);
            }
        }
    } else {
        // ---- K/V region: f32 outputs direct; bf16 via LDS transpose ----
        const bool isV = (n0 >= 2560);
        const int base = isV ? 2560 : 2048;
        __syncthreads();                       // staging LDS now dead
#pragma unroll
        for (int nt = 0; nt < 4; nt++) {
            int col = n0 + wn + nt * 16 + ln15;
            int cl = wn + nt * 16 + ln15;      // block-local col 0..127
            float bv = bias[col];
            int gc = col - base, g = gc >> 6, d = gc & 63;
#pragma unroll
            for (int mt = 0; mt < 4; mt++) {
                int rl0 = wm + mt * 16 + quad * 4;
#pragma unroll
                for (int r = 0; r < 4; r++) {
                    float val = acc[mt][nt][r] + bv;
                    int s = s0 + rl0 + r;
                    size_t idx = (((size_t)(bb * NG + g) * S_LEN + s) << 6) + d;
                    if (isV) Vg[idx] = val; else Kg[idx] = val;
                    lds[(size_t)cl * 136 + rl0 + r] = f2b(val);
                }
            }
        }
        __syncthreads();
        const int g0 = (n0 - base) >> 6;
        if (isV) {
            // Vtb[((bb*NG+g)*DK + d) * S + s]: 128B-contiguous along s
            int cl = tid >> 1, sh = (tid & 1) * 64;
            int g = g0 + (cl >> 6), d = cl & 63;
            unsigned short* dst = &Vtb[((size_t)(bb * NG + g) * DK + d) * S_LEN + s0 + sh];
            const unsigned short* src = &lds[(size_t)cl * 136 + sh];
#pragma unroll
            for (int j = 0; j < 8; j++)
                *(s16x8*)(dst + j * 8) = *(const s16x8*)(src + j * 8);
        } else {
            // Kb[((bb*NG+g)*S + s)*64 + d]: 128B-contiguous along d
            int srow = tid >> 1, gh = tid & 1;
            int g = g0 + gh;
            unsigned short* dst = &Kb[(((size_t)(bb * NG + g) * S_LEN + s0 + srow) << 6)];
#pragma unroll
            for (int jo = 0; jo < 8; jo++) {
                s16x8 v;
#pragma unroll
                for (int j = 0; j < 8; j++)
                    v[j] = (short)lds[(size_t)(gh * 64 + jo * 8 + j) * 136 + srow];
                *(s16x8*)(dst + jo * 8) = v;
            }
        }
    }
#undef AS
#undef BS
}

// ============ O-projection (v9-proven): 3-buffer counted vmcnt(4) ===========
__global__ __launch_bounds__(256, 3) void gemm_o(const unsigned short* __restrict__ A,
                                              const unsigned short* __restrict__ Bt,
                                              const float* __restrict__ bias,
                                              float* __restrict__ C) {
    __shared__ alignas(16) unsigned short As[3][128 * 32];
    __shared__ alignas(16) unsigned short Bs[3][128 * 32];
    const int K = DM, N = DM;
    const int tid = threadIdx.x;
    int bx, by;
    xcd_remap(DM / 128, &bx, &by);
    const int n0 = bx * 128, m0 = by * 128;
    const int w = tid >> 6, lane = tid & 63;
    const int ln15 = lane & 15, quad = lane >> 4;
    const int wm = (w >> 1) * 64, wn = (w & 1) * 64;
    const int xq = (quad ^ ((ln15 >> 1) & 3)) * 8;
    f32x4 acc[4][4] = {};

#define GSTAGE(k0v, buf) do {                                                    \
    _Pragma("unroll")                                                            \
    for (int i = 0; i < 2; ++i) {                                                \
        int s = w * 128 + i * 64 + lane;                                         \
        int r = s >> 2, cb = (s & 3) ^ ((r >> 1) & 3);                           \
        gl_lds(&A[(size_t)(m0 + r) * K + (k0v) + cb * 8],                        \
               &As[buf][(w * 128 + i * 64) * 8]);                                \
        gl_lds(&Bt[(size_t)(n0 + r) * K + (k0v) + cb * 8],                       \
               &Bs[buf][(w * 128 + i * 64) * 8]);                                \
    } } while (0)

    GSTAGE(0, 0);
    GSTAGE(32, 1);
    int cur = 0;
    for (int k0 = 0; k0 < K; k0 += 32) {
        if (k0 + 32 < K) wait_vm4(); else wait_vm0();
        bar();
        if (k0 + 64 < K) {
            int nb = cur + 2; if (nb >= 3) nb -= 3;
            GSTAGE(k0 + 64, nb);
        }
        bf16x8 af[4], bfr[4];
#pragma unroll
        for (int mt = 0; mt < 4; mt++)
            af[mt] = ld8(&As[cur][(wm + mt * 16 + ln15) * 32 + xq]);
#pragma unroll
        for (int nt = 0; nt < 4; nt++)
            bfr[nt] = ld8(&Bs[cur][(wn + nt * 16 + ln15) * 32 + xq]);
        __builtin_amdgcn_s_setprio(1);
#pragma unroll
        for (int mt = 0; mt < 4; mt++)
#pragma unroll
            for (int nt = 0; nt < 4; nt++)
                acc[mt][nt] = __builtin_amdgcn_mfma_f32_16x16x32_bf16(af[mt], bfr[nt], acc[mt][nt], 0, 0, 0);
        __builtin_amdgcn_s_setprio(0);
        cur = (cur + 1 == 3) ? 0 : cur + 1;
    }
#undef GSTAGE
#pragma unroll
    for (int nt = 0; nt < 4; nt++) {
        int col = n0 + wn + nt * 16 + ln15;
        float bv = bias[col];
#pragma unroll
        for (int mt = 0; mt < 4; mt++) {
            int row0 = m0 + wm + mt * 16 + quad * 4;
#pragma unroll
            for (int r = 0; r < 4; r++)
                C[(size_t)(row0 + r) * N + col] = acc[mt][nt][r] + bv;
        }
    }
}

// ============ flash attention v12 (kept): KVBLK=128, 512 threads ============
#define MT 2                 /* 16-row mfma blocks per wave */
__global__ __launch_bounds__(512, 4) void attn_fwd(const unsigned short* __restrict__ Qb,
                                                   const unsigned short* __restrict__ Kb,
                                                   const unsigned short* __restrict__ Vtb,
                                                   unsigned short* __restrict__ AO) {
    __shared__ alignas(16) unsigned short Ks[2][2][64 * 64];  // [buf][sub][r][cb^(r&7)]
    __shared__ alignas(16) unsigned short Vt[2][2][64 * 64];  // rows = d
    const int b = blockIdx.z, h = blockIdx.y, q0 = blockIdx.x * 256;
    const int g = h >> 2;
    const int tid = threadIdx.x;
    const int w = tid >> 6, lane = tid & 63;
    const int ln15 = lane & 15, quad = lane >> 4;
    const int x7a = (quad ^ (ln15 & 7)) * 8;        // k-block 0..3 swizzled
    const int x7b = x7a ^ 32;                       // k-block 4..7 swizzled

    // Q fragments for this wave's 32 q rows (MT mfma row-blocks); pre-scaled
    bf16x8 aq[MT][2];
#pragma unroll
    for (int mt = 0; mt < MT; mt++) {
        const size_t qrow =
            ((size_t)(b * S_LEN + q0 + w * 32 + mt * 16 + ln15)) * DM + h * DK;
        aq[mt][0] = ld8(&Qb[qrow + quad * 8]);
        aq[mt][1] = ld8(&Qb[qrow + 32 + quad * 8]);
    }

    bf16x8 ones;
#pragma unroll
    for (int j = 0; j < 8; j++) ones[j] = (__bf16)1.0f;

    f32x4 o[MT][4] = {};     // [mt][nt]  D[q][d]: col=ln15, row=quad*4+r
    f32x4 l_acc[MT] = {};    // [mt]
    const size_t kvb = ((size_t)(b * NG + g)) * S_LEN * DK;

    // 512 threads: per sub-tile, one K + one V gl_lds per thread (512 slots).
#define STAGE(k0v, buf) do {                                                     \
    int r = tid >> 3, cb = (tid & 7) ^ (r & 7);                                  \
    _Pragma("unroll")                                                            \
    for (int j = 0; j < 2; j++) {                                                \
        gl_lds(&Kb[kvb + (size_t)((k0v) + j * 64 + r) * DK + cb * 8],            \
               &Ks[buf][j][(w * 64) * 8]);                                       \
        gl_lds(&Vtb[kvb + (size_t)r * S_LEN + (k0v) + j * 64 + cb * 8],          \
               &Vt[buf][j][(w * 64) * 8]);                                       \
    } } while (0)

    STAGE(0, 0);
    wait_vm0();
    __syncthreads();
    int cur = 0;

    for (int k0 = 0; k0 < S_LEN; k0 += 128) {
        if (k0 + 128 < S_LEN) STAGE(k0 + 128, cur ^ 1);   // prefetch next pair

#pragma unroll
        for (int sub = 0; sub < 2; sub++) {
            // ---- QK^T (swapped): z[mt][nt] = D[key][q=mt*16+ln15]
            f32x4 z[MT][4];
            __builtin_amdgcn_s_setprio(1);
#pragma unroll
            for (int nt = 0; nt < 4; nt++) {
                bf16x8 bk0 = ld8(&Ks[cur][sub][(nt * 16 + ln15) * 64 + x7a]);
                bf16x8 bk1 = ld8(&Ks[cur][sub][(nt * 16 + ln15) * 64 + x7b]);
#pragma unroll
                for (int mt = 0; mt < MT; mt++) {
                    f32x4 t = {0.f, 0.f, 0.f, 0.f};
                    t = __builtin_amdgcn_mfma_f32_16x16x32_bf16(bk0, aq[mt][0], t, 0, 0, 0);
                    t = __builtin_amdgcn_mfma_f32_16x16x32_bf16(bk1, aq[mt][1], t, 0, 0, 0);
                    z[mt][nt] = t;
                }
            }
            __builtin_amdgcn_s_setprio(0);

            // ---- exp2 + pack + in-register transpose to PV A-fragments ----
            bf16x8 pa[MT][2];
#pragma unroll
            for (int mt = 0; mt < MT; mt++) {
                unsigned int S[4][2];
#pragma unroll
                for (int nt = 0; nt < 4; nt++) {
                    f32x4 pe;
#pragma unroll
                    for (int r = 0; r < 4; r++)
                        pe[r] = __builtin_amdgcn_exp2f(z[mt][nt][r]);
                    asm("v_cvt_pk_bf16_f32 %0, %1, %2" : "=v"(S[nt][0]) : "v"(pe[0]), "v"(pe[1]));
                    asm("v_cvt_pk_bf16_f32 %0, %1, %2" : "=v"(S[nt][1]) : "v"(pe[2]), "v"(pe[3]));
                }
#pragma unroll
                for (int f = 0; f < 2; f++) {
                    unsigned int wA[2], wB[2];
#pragma unroll
                    for (int p = 0; p < 2; p++) {
                        unsigned int xa = S[2 * f][p], yb = S[2 * f + 1][p];
                        asm("v_permlane32_swap_b32 %0, %1" : "+v"(xa), "+v"(yb));
                        asm("v_permlane16_swap_b32 %0, %1" : "+v"(xa), "+v"(yb));
                        wA[p] = xa; wB[p] = yb;
                    }
                    u32x4 t4;
                    t4[0] = wA[0]; t4[1] = wA[1]; t4[2] = wB[0]; t4[3] = wB[1];
                    pa[mt][f] = __builtin_bit_cast(bf16x8, t4);
                }
            }

            // ---- PV: nt outer so each V fragment is read once ----
            __builtin_amdgcn_s_setprio(1);
#pragma unroll
            for (int nt = 0; nt < 4; nt++) {
                bf16x8 bv0 = ld8(&Vt[cur][sub][(nt * 16 + ln15) * 64 + x7a]);
                bf16x8 bv1 = ld8(&Vt[cur][sub][(nt * 16 + ln15) * 64 + x7b]);
#pragma unroll
                for (int mt = 0; mt < MT; mt++) {
                    f32x4 t = o[mt][nt];
                    t = __builtin_amdgcn_mfma_f32_16x16x32_bf16(pa[mt][0], bv0, t, 0, 0, 0);
                    t = __builtin_amdgcn_mfma_f32_16x16x32_bf16(pa[mt][1], bv1, t, 0, 0, 0);
                    o[mt][nt] = t;
                }
            }
#pragma unroll
            for (int mt = 0; mt < MT; mt++) {
                l_acc[mt] = __builtin_amdgcn_mfma_f32_16x16x32_bf16(pa[mt][0], ones, l_acc[mt], 0, 0, 0);
                l_acc[mt] = __builtin_amdgcn_mfma_f32_16x16x32_bf16(pa[mt][1], ones, l_acc[mt], 0, 0, 0);
            }
            __builtin_amdgcn_s_setprio(0);
        }

        wait_vm0();          // drain prefetch before buffer flip
        __syncthreads();
        cur ^= 1;
    }
#undef STAGE

#pragma unroll
    for (int mt = 0; mt < MT; mt++) {
#pragma unroll
        for (int r = 0; r < 4; r++) {
            float inv = 1.0f / l_acc[mt][r];
            int q = q0 + w * 32 + mt * 16 + quad * 4 + r;
#pragma unroll
            for (int nt = 0; nt < 4; nt++) {
                int col = h * DK + nt * 16 + ln15;
                *(__bf16*)&AO[((size_t)(b * S_LEN + q)) * DM + col] =
                    (__bf16)(o[mt][nt][r] * inv);
            }
        }
    }
}

extern "C" void kernel_launch(void* const* d_in, const int* in_sizes, int n_in,
                              void* d_out, int out_size, void* d_ws, size_t ws_size,
                              hipStream_t stream) {
    const float* x  = (const float*)d_in[0];
    const float* Wq = (const float*)d_in[1];
    const float* bq = (const float*)d_in[2];
    const float* Wk = (const float*)d_in[3];
    const float* bk = (const float*)d_in[4];
    const float* Wv = (const float*)d_in[5];
    const float* bv = (const float*)d_in[6];
    const float* Wo = (const float*)d_in[7];
    const float* bo = (const float*)d_in[8];

    float* out = (float*)d_out;                         // [4096, 2048] f32
    float* Kg  = out + (size_t)MROWS * DM;              // (B,G,S,dk) f32
    float* Vg  = Kg + (size_t)BATCH * NG * S_LEN * DK;

    // Qb bf16 [4096,2048] parks in the out region (proven safe rounds 4-5);
    // it is only READ via plain vector loads, never via global_load_lds.
    unsigned short* Qb = (unsigned short*)d_out;

    // workspace layout (62.93 MB). All global_load_lds sources live here.
    unsigned short* ws    = (unsigned short*)d_ws;
    unsigned short* WqkvT = ws;                                   // [3072,2048] bf16
    unsigned short* WoT   = WqkvT + (size_t)NQKV * DM;            // [2048,2048] bf16
    unsigned short* Kb    = WoT + (size_t)DM * DM;                // (B,G,S,dk) bf16
    unsigned short* Vtb   = Kb + (size_t)BATCH * NG * S_LEN * DK; // (B,G,dk,S) bf16
    unsigned short* AO    = Vtb + (size_t)BATCH * NG * S_LEN * DK;// [4096,2048] bf16
    unsigned short* xb    = AO + (size_t)MROWS * DM;              // [4096,2048] bf16
    float*          bqkv  = (float*)(xb + (size_t)MROWS * DM);    // [3072] f32

    hipLaunchKernelGGL(prep_fused, dim3(NPREP), dim3(32, 8), 0, stream,
                       x, Wq, Wk, Wv, Wo, bq, bk, bv, xb, WqkvT, WoT, bqkv);

    hipLaunchKernelGGL(gemm_qkv, dim3(NQKV / 128, MROWS / 128), dim3(256), 0, stream,
                       xb, WqkvT, bqkv, Qb, Kg, Vg, Kb, Vtb);

    hipLaunchKernelGGL(attn_fwd, dim3(S_LEN / 256, NH, BATCH), dim3(512), 0, stream,
                       Qb, Kb, Vtb, AO);

    hipLaunchKernelGGL(gemm_o, dim3(DM / 128, MROWS / 128), dim3(256), 0, stream,
                       AO, WoT, bo, out);
}